// Round 5
// baseline (184.400 us; speedup 1.0000x reference)
//
#include <hip/hip_runtime.h>

// Problem constants
#define N_TOK 8192
#define N_EXP 8
#define DIM   2048
#define HID   2048

typedef __attribute__((ext_vector_type(8))) short short8;
typedef __attribute__((ext_vector_type(4))) float f32x4;
typedef __attribute__((ext_vector_type(4))) unsigned short ushort4v;

__device__ inline unsigned short f2bf(float f) {
  unsigned int u = __builtin_bit_cast(unsigned int, f);
  unsigned int r = u + 0x7FFFu + ((u >> 16) & 1u);   // round-to-nearest-even
  return (unsigned short)(r >> 16);
}

// ---------------------------------------------------------------------------
// Kernel 1: stable counting sort by expert id. One block, 256 threads.
// ---------------------------------------------------------------------------
__global__ __launch_bounds__(256) void sort_experts(const int* __restrict__ idx,
                                                    int* __restrict__ perm,
                                                    int* __restrict__ offs) {
  __shared__ int cnt[256][8];
  __shared__ int base[8];
  const int t = threadIdx.x;
  int local[8] = {0,0,0,0,0,0,0,0};
  const int r0 = t * 32;
  for (int i = 0; i < 32; ++i) {
    int e = idx[r0 + i] & 7;
    ++local[e];
  }
#pragma unroll
  for (int e = 0; e < 8; ++e) cnt[t][e] = local[e];
  __syncthreads();
  if (t < 8) {
    int s = 0;
    for (int i = 0; i < 256; ++i) { int v = cnt[i][t]; cnt[i][t] = s; s += v; }
    base[t] = s;
  }
  __syncthreads();
  if (t == 0) {
    int s = 0;
    for (int e = 0; e < 8; ++e) { int v = base[e]; offs[e] = s; base[e] = s; s += v; }
    offs[8] = s;
  }
  __syncthreads();
  int pos[8];
#pragma unroll
  for (int e = 0; e < 8; ++e) pos[e] = base[e] + cnt[t][e];
  for (int i = 0; i < 32; ++i) {
    int r = r0 + i;
    int e = idx[r] & 7;
    perm[pos[e]++] = r;
  }
}

// ---------------------------------------------------------------------------
// Kernel 2: gather rows into sorted order + fp32 -> bf16.
// ---------------------------------------------------------------------------
__global__ __launch_bounds__(256) void gather_convert_x(const float* __restrict__ x,
                                                        const int* __restrict__ perm,
                                                        unsigned short* __restrict__ xs) {
  int gid = blockIdx.x * 256 + threadIdx.x;
  int p = gid >> 8;
  int c = gid & 255;
  int src = perm[p];
  const float* sp = x + (size_t)src * DIM + c * 8;
  float4 a = *(const float4*)sp;
  float4 b = *(const float4*)(sp + 4);
  short8 o;
  o[0] = (short)f2bf(a.x); o[1] = (short)f2bf(a.y);
  o[2] = (short)f2bf(a.z); o[3] = (short)f2bf(a.w);
  o[4] = (short)f2bf(b.x); o[5] = (short)f2bf(b.y);
  o[6] = (short)f2bf(b.z); o[7] = (short)f2bf(b.w);
  *(short8*)(xs + (size_t)p * DIM + c * 8) = o;
}

// ---------------------------------------------------------------------------
// Kernel 3: W[e][d][h] fp32 -> Wt[e][h][d] bf16 (LDS-tiled transpose).
// ---------------------------------------------------------------------------
__global__ __launch_bounds__(256) void transpose_convert_w(const float* __restrict__ W,
                                                           unsigned short* __restrict__ Wt) {
  __shared__ unsigned short tile[64][68];
  const int e = blockIdx.z;
  const int d0 = blockIdx.y * 64;
  const int h0 = blockIdx.x * 64;
  const int t = threadIdx.x;
  const int cr = t & 15;
  const int rr = t >> 4;
  const float* Wp = W + ((size_t)e * DIM + d0) * HID + h0;
#pragma unroll
  for (int i = 0; i < 4; ++i) {
    int d = rr + i * 16;
    float4 v = *(const float4*)(Wp + (size_t)d * HID + cr * 4);
    ushort4v o;
    o[0] = f2bf(v.x); o[1] = f2bf(v.y); o[2] = f2bf(v.z); o[3] = f2bf(v.w);
    *(ushort4v*)&tile[d][cr * 4] = o;
  }
  __syncthreads();
  unsigned short* op = Wt + ((size_t)e * HID + h0) * DIM + d0;
#pragma unroll
  for (int i = 0; i < 4; ++i) {
    int h = rr + i * 16;
    ushort4v o;
    o[0] = tile[cr * 4 + 0][h];
    o[1] = tile[cr * 4 + 1][h];
    o[2] = tile[cr * 4 + 2][h];
    o[3] = tile[cr * 4 + 3][h];
    *(ushort4v*)(op + (size_t)h * DIM + cr * 4) = o;
  }
}

// ---------------------------------------------------------------------------
// Kernel 4: grouped GEMM — 128x128 tile, BK=32, 4 waves (2M x 2N, per-wave
// 64x64), FOUR 16KB LDS slots (64 KiB total -> 2 blocks/CU co-resident for
// cross-block stall hiding). One fat phase per K-tile: 8 ds_read_b128 +
// 4 gload_lds (tile T+3) + barrier + setprio(1) + 16 MFMA + setprio(0) +
// vmcnt(8) + barrier. Swizzle for 64B rows: byte[5:4] ^= row[1:0], inverse
// pre-applied to global staging sources (rule 21).
// ---------------------------------------------------------------------------
#define NKT 64          // K-tiles of 32
#define SLOT 8192       // ushorts per slot (16KB): A [0,4096) B [4096,8192)

#define MM(D,A,B) D = __builtin_amdgcn_mfma_f32_16x16x32_bf16(A, B, D, 0, 0, 0)
#define GLD(SRC, DST) __builtin_amdgcn_global_load_lds( \
    (const __attribute__((address_space(1))) void*)(SRC), \
    (__attribute__((address_space(3))) void*)(DST), 16, 0, 0)
#define BAR() __builtin_amdgcn_s_barrier()
#define PRIO(x) __builtin_amdgcn_s_setprio(x)

__global__ __launch_bounds__(256, 2) void grouped_gemm(
    const unsigned short* __restrict__ xs,
    const unsigned short* __restrict__ Wt,
    const float* __restrict__ bias,
    const int* __restrict__ offs,
    float* __restrict__ out) {
  const int e   = blockIdx.z;
  const int off = offs[e];
  const int cnt = offs[e + 1] - off;
  const int mt  = blockIdx.y;
  if (mt * 128 >= cnt) return;
  const int n0 = blockIdx.x * 128;

  __shared__ __align__(16) unsigned short sm[4 * SLOT];   // 64 KiB

  const int t    = threadIdx.x;
  const int lane = t & 63;
  const int wid  = t >> 6;
  const int wr   = wid >> 1;   // 0..1  (M half: rows wr*64)
  const int wc   = wid & 1;    // 0..1  (N half: cols wc*64)
  const int l15  = lane & 15;
  const int l4   = lane >> 4;

  // Fragment LDS offsets (ushort units); row stride 32 ush (64B).
  // Swizzle: 16B-slot index ^= row[1:0]; row[1:0] == l15&3 for all frags.
  const int ksw = (l4 ^ (l15 & 3)) * 8;               // swizzled k-offset
  const int arow = (wr * 64 + l15) * 32;              // + m*512
  const int brow = 4096 + (wc * 64 + l15) * 32;       // + n*512

  // Staging sources: chunk thread t covers row r0 = t>>2 (of a 64-row chunk),
  // 16B slot t&3; inverse swizzle pre-applied to global k index.
  const int r0  = t >> 2;
  const int keu = ((t & 3) ^ (r0 & 3)) * 8;
  const int aBase = off + mt * 128;
  const int dA = t * 8;   // linear LDS dest (ushort) within a 4KB chunk

  unsigned int pa0, pa1, pb0, pb1;
  {
    int p;
    p = aBase + 0 * 64 + r0; if (p > N_TOK - 1) p = N_TOK - 1; pa0 = (unsigned)p * 2048 + keu;
    p = aBase + 1 * 64 + r0; if (p > N_TOK - 1) p = N_TOK - 1; pa1 = (unsigned)p * 2048 + keu;
    unsigned int eW = (unsigned)e * (DIM * HID);
    pb0 = eW + (unsigned)(n0 + 0 * 64 + r0) * 2048 + keu;
    pb1 = eW + (unsigned)(n0 + 1 * 64 + r0) * 2048 + keu;
  }

#define ST_TILE(SBASE, KOFS) do { \
    GLD(xs + pa0 + (KOFS), sm + (SBASE) + 0 * 2048 + dA); \
    GLD(xs + pa1 + (KOFS), sm + (SBASE) + 1 * 2048 + dA); \
    GLD(Wt + pb0 + (KOFS), sm + (SBASE) + 4096 + 0 * 2048 + dA); \
    GLD(Wt + pb1 + (KOFS), sm + (SBASE) + 4096 + 1 * 2048 + dA); } while (0)

  f32x4 acc[4][4] = {};

  // Prologue: stage tiles 0,1,2 into slots 0,1,2 (4 loads each).
  ST_TILE(0 * SLOT, 0);
  ST_TILE(1 * SLOT, 32);
  ST_TILE(2 * SLOT, 64);
  asm volatile("s_waitcnt vmcnt(8)" ::: "memory");   // tile0 landed
  BAR();

  short8 fa0, fa1, fa2, fa3, fb0, fb1, fb2, fb3;

#pragma unroll 1
  for (int T = 0; T < NKT; ++T) {
    const unsigned short* SP = sm + (T & 3) * SLOT;

    fa0 = *(const short8*)(SP + arow + 0 * 512 + ksw);
    fa1 = *(const short8*)(SP + arow + 1 * 512 + ksw);
    fa2 = *(const short8*)(SP + arow + 2 * 512 + ksw);
    fa3 = *(const short8*)(SP + arow + 3 * 512 + ksw);
    fb0 = *(const short8*)(SP + brow + 0 * 512 + ksw);
    fb1 = *(const short8*)(SP + brow + 1 * 512 + ksw);
    fb2 = *(const short8*)(SP + brow + 2 * 512 + ksw);
    fb3 = *(const short8*)(SP + brow + 3 * 512 + ksw);

    if (T < NKT - 3) ST_TILE(((T + 3) & 3) * SLOT, (T + 3) * 32);

    BAR(); PRIO(1);
    MM(acc[0][0],fa0,fb0); MM(acc[0][1],fa0,fb1); MM(acc[0][2],fa0,fb2); MM(acc[0][3],fa0,fb3);
    MM(acc[1][0],fa1,fb0); MM(acc[1][1],fa1,fb1); MM(acc[1][2],fa1,fb2); MM(acc[1][3],fa1,fb3);
    MM(acc[2][0],fa2,fb0); MM(acc[2][1],fa2,fb1); MM(acc[2][2],fa2,fb2); MM(acc[2][3],fa2,fb3);
    MM(acc[3][0],fa3,fb0); MM(acc[3][1],fa3,fb1); MM(acc[3][2],fa3,fb2); MM(acc[3][3],fa3,fb3);
    PRIO(0);
    // Guarantee tile T+1 landed before any wave reads it next phase.
    // Outstanding after phase-T stage: tiles T+2, T+3 (8 loads).
    if (T < NKT - 3)       { asm volatile("s_waitcnt vmcnt(8)" ::: "memory"); }
    else if (T == NKT - 3) { asm volatile("s_waitcnt vmcnt(4)" ::: "memory"); }
    else if (T == NKT - 2) { asm volatile("s_waitcnt vmcnt(0)" ::: "memory"); }
    BAR();
  }

  // Epilogue: bias + relu, masked tail rows.
#pragma unroll
  for (int n = 0; n < 4; ++n) {
    int col = n0 + wc * 64 + n * 16 + l15;
    float bv = bias[e * HID + col];
#pragma unroll
    for (int m = 0; m < 4; ++m) {
#pragma unroll
      for (int q = 0; q < 4; ++q) {
        int r = wr * 64 + m * 16 + l4 * 4 + q;
        if (mt * 128 + r < cnt) {
          float v = acc[m][n][q] + bv;
          out[(size_t)(off + mt * 128 + r) * HID + col] = v > 0.f ? v : 0.f;
        }
      }
    }
  }
}

// ---------------------------------------------------------------------------
extern "C" void kernel_launch(void* const* d_in, const int* in_sizes, int n_in,
                              void* d_out, int out_size, void* d_ws, size_t ws_size,
                              hipStream_t stream) {
  const float* x   = (const float*)d_in[0];
  const int*   idx = (const int*)d_in[1];
  const float* W   = (const float*)d_in[2];
  const float* b   = (const float*)d_in[3];
  float* out = (float*)d_out;

  char* ws = (char*)d_ws;
  unsigned short* xs = (unsigned short*)ws;                                   // 32 MB
  unsigned short* Wt = (unsigned short*)(ws + (size_t)N_TOK * DIM * 2);       // 64 MB
  int* perm = (int*)(ws + (size_t)N_TOK * DIM * 2 + (size_t)N_EXP * DIM * HID * 2);
  int* offs = perm + N_TOK;

  sort_experts<<<1, 256, 0, stream>>>(idx, perm, offs);
  gather_convert_x<<<N_TOK * (DIM / 8) / 256, 256, 0, stream>>>(x, perm, xs);
  transpose_convert_w<<<dim3(HID / 64, DIM / 64, N_EXP), 256, 0, stream>>>(W, Wt);
  grouped_gemm<<<dim3(HID / 128, N_TOK / 128, N_EXP), 256, 0, stream>>>(xs, Wt, b, offs, out);
}